// Round 5
// baseline (293.432 us; speedup 1.0000x reference)
//
#include <hip/hip_runtime.h>
#include <math.h>

#define N_NODES 50000
#define N_EDGES 800000
#define NFEAT 256
#define NHID 64
#define NCLASS 40
#define NPAD_ROWS 50048   // gemm2 reads h in 64-row blocks: 782*64
#define NPB 16            // nodes per bucket
#define NB  3125          // 50000 / 16
#define NSEG 7            // segments of 131072 edges (e >> 17), max s = 6
#define SEGSH 17

typedef __attribute__((ext_vector_type(8))) short bf16x8;
typedef __attribute__((ext_vector_type(4))) float f32x4;

__device__ __forceinline__ ushort f2bf(float f) {
    unsigned u = __float_as_uint(f);
    u += 0x7FFF + ((u >> 16) & 1);          // round-to-nearest-even
    return (ushort)(u >> 16);
}
__device__ __forceinline__ float bf2f(ushort us) {
    return __uint_as_float(((unsigned)us) << 16);
}

// ---------------- bucket CSR build (flat, segmented counters) ----------------

__global__ void k_bhist(const int* __restrict__ edst, int* __restrict__ bcnt) {
    int e = blockIdx.x * 256 + threadIdx.x;
    if (e < N_EDGES) {
        int s = e >> SEGSH;
        atomicAdd(&bcnt[s * NB + (edst[e] >> 4)], 1);
    }
}

// Wave-aggregated allocation of disjoint (s,b) ranges; global order irrelevant.
__global__ void k_bscan(const int* __restrict__ bcnt, int* __restrict__ bstart,
                        int* __restrict__ bcur, int* __restrict__ cursor) {
    int i = blockIdx.x * 256 + threadIdx.x;
    int lane = threadIdx.x & 63;
    int c = (i < NSEG * NB) ? bcnt[i] : 0;
    int incl = c;
    #pragma unroll
    for (int off = 1; off < 64; off <<= 1) {
        int n = __shfl_up(incl, off);
        if (lane >= off) incl += n;
    }
    int total = __shfl(incl, 63);
    int base = 0;
    if (lane == 0) base = atomicAdd(cursor, total);
    base = __shfl(base, 0);
    if (i < NSEG * NB) {
        int s = base + incl - c;
        bstart[i] = s;
        bcur[i] = s;
    }
}

// Flat scatter: claim slot in (segment,bucket) range, store packed payload.
__global__ void k_bin(const int* __restrict__ esrc, const int* __restrict__ edst,
                      const float* __restrict__ ewt, int* __restrict__ bcur,
                      int2* __restrict__ binned) {
    int e = blockIdx.x * 256 + threadIdx.x;
    if (e < N_EDGES) {
        int d = edst[e];
        int s = e >> SEGSH;
        int pos = atomicAdd(&bcur[s * NB + (d >> 4)], 1);
        binned[pos] = make_int2(esrc[e] | ((d & 15) << 16), __float_as_int(ewt[e]));
    }
}

// ---------------- prep: W1,W2 -> bf16 fragment-ordered tables ----------------

__global__ void k_prep(const float* __restrict__ W1, const float* __restrict__ W2,
                       ushort* __restrict__ W1f, ushort* __restrict__ W2f) {
    int idx = blockIdx.x * 256 + threadIdx.x;
    if (idx < 2048) {                        // 4 ct * 8 ks * 64 lanes
        int lane = idx & 63, ctks = idx >> 6;
        int ks = ctks & 7, ct = ctks >> 3;
        int col = ct * 16 + (lane & 15);
        int r0 = ks * 32 + (lane >> 4) * 8;
        bf16x8 frag;
        #pragma unroll
        for (int j = 0; j < 8; ++j) frag[j] = (short)f2bf(W1[(r0 + j) * NHID + col]);
        *(bf16x8*)&W1f[(size_t)idx * 8] = frag;
    } else if (idx < 2048 + 384) {           // 3 ct * 2 ks * 64 lanes
        int i2 = idx - 2048;
        int lane = i2 & 63, ctks = i2 >> 6;
        int ks = ctks & 1, ct = ctks >> 1;
        int col = ct * 16 + (lane & 15);
        int r0 = ks * 32 + (lane >> 4) * 8;
        bf16x8 frag;
        #pragma unroll
        for (int j = 0; j < 8; ++j)
            frag[j] = (short)((col < NCLASS) ? f2bf(W2[(r0 + j) * NCLASS + col]) : 0);
        *(bf16x8*)&W2f[(size_t)i2 * 8] = frag;
    }
}

// ---------------- GEMM1: xW1b = bf16( x @ W1 ) via MFMA ----------------

__global__ __launch_bounds__(256) void k_gemm1(const float* __restrict__ x,
                                               const ushort* __restrict__ W1f,
                                               ushort* __restrict__ xW1b) {
    __shared__ ushort sX[16 * 256];          // 8 KB
    int tid = threadIdx.x;
    int w = tid >> 6, lane = tid & 63;
    int row0 = blockIdx.x * 16;

    bf16x8 Bf[8];
    #pragma unroll
    for (int ks = 0; ks < 8; ++ks)
        Bf[ks] = *(const bf16x8*)&W1f[(size_t)((w * 8 + ks) * 64 + lane) * 8];

    {
        int row = tid & 15;
        int colbase = (tid >> 4) * 16;
        const float* xp = x + (size_t)(row0 + row) * NFEAT + colbase;
        #pragma unroll
        for (int c2 = 0; c2 < 2; ++c2) {
            float4 v0 = *(const float4*)(xp + c2 * 8);
            float4 v1 = *(const float4*)(xp + c2 * 8 + 4);
            bf16x8 fr;
            fr[0] = (short)f2bf(v0.x); fr[1] = (short)f2bf(v0.y);
            fr[2] = (short)f2bf(v0.z); fr[3] = (short)f2bf(v0.w);
            fr[4] = (short)f2bf(v1.x); fr[5] = (short)f2bf(v1.y);
            fr[6] = (short)f2bf(v1.z); fr[7] = (short)f2bf(v1.w);
            int chunk = colbase / 8 + c2;                 // 0..31
            *(bf16x8*)&sX[row * 256 + ((chunk ^ (row & 7)) * 8)] = fr;
        }
    }
    __syncthreads();

    f32x4 acc = {0.f, 0.f, 0.f, 0.f};
    int arow = lane & 15;
    #pragma unroll
    for (int ks = 0; ks < 8; ++ks) {
        int chunk = ks * 4 + (lane >> 4);
        bf16x8 Af = *(const bf16x8*)&sX[arow * 256 + ((chunk ^ (arow & 7)) * 8)];
        acc = __builtin_amdgcn_mfma_f32_16x16x32_bf16(Af, Bf[ks], acc, 0, 0, 0);
    }
    int col = w * 16 + (lane & 15);
    int rbase = row0 + (lane >> 4) * 4;
    #pragma unroll
    for (int r = 0; r < 4; ++r)
        xW1b[(size_t)(rbase + r) * NHID + col] = f2bf(acc[r]);
}

// ---------------- SPMM1 (bucketed) + bias + ReLU -> h (bf16) ----------------
// One wave per 16-node bucket; 7 segment ranges. Column `lane` thread-private.
__global__ __launch_bounds__(64) void k_spmm1b(const ushort* __restrict__ xW1b,
                                               const int* __restrict__ bstart,
                                               const int* __restrict__ bcur,
                                               const int2* __restrict__ binned,
                                               const float* __restrict__ b1,
                                               ushort* __restrict__ h_b) {
    __shared__ float acc[NPB * NHID];        // 4 KB
    int lane = threadIdx.x;
    int b = blockIdx.x;
    #pragma unroll
    for (int n = 0; n < NPB; ++n) acc[n * NHID + lane] = 0.f;

    for (int s = 0; s < NSEG; ++s) {
        int j = bstart[s * NB + b], e = bcur[s * NB + b];
        for (; j + 8 <= e; j += 8) {
            int2 p[8];
            #pragma unroll
            for (int k = 0; k < 8; ++k) p[k] = binned[j + k];
            float g[8];
            #pragma unroll
            for (int k = 0; k < 8; ++k)
                g[k] = bf2f(xW1b[(p[k].x & 0xFFFF) * NHID + lane]);
            #pragma unroll
            for (int k = 0; k < 8; ++k)
                acc[(p[k].x >> 16) * NHID + lane] += __int_as_float(p[k].y) * g[k];
        }
        for (; j < e; ++j) {
            int2 p0 = binned[j];
            float g0 = bf2f(xW1b[(p0.x & 0xFFFF) * NHID + lane]);
            acc[(p0.x >> 16) * NHID + lane] += __int_as_float(p0.y) * g0;
        }
    }

    float bias = b1[lane];
    #pragma unroll
    for (int n = 0; n < NPB; ++n) {
        float v = acc[n * NHID + lane] + bias;
        h_b[(size_t)(b * NPB + n) * NHID + lane] = f2bf(v > 0.f ? v : 0.f);
    }
}

// ---------------- GEMM2: hW2b = bf16( h @ W2 ) via MFMA ----------------

__global__ __launch_bounds__(256) void k_gemm2(const ushort* __restrict__ h_b,
                                               const ushort* __restrict__ W2f,
                                               ushort* __restrict__ hW2b) {
    int tid = threadIdx.x;
    int w = tid >> 6, lane = tid & 63;
    int row0 = blockIdx.x * 64 + w * 16;

    f32x4 acc[3] = {{0.f,0.f,0.f,0.f},{0.f,0.f,0.f,0.f},{0.f,0.f,0.f,0.f}};
    #pragma unroll
    for (int ks = 0; ks < 2; ++ks) {
        bf16x8 Af = *(const bf16x8*)&h_b[(size_t)(row0 + (lane & 15)) * NHID
                                         + ks * 32 + (lane >> 4) * 8];
        #pragma unroll
        for (int ct = 0; ct < 3; ++ct) {
            bf16x8 Bf = *(const bf16x8*)&W2f[(size_t)((ct * 2 + ks) * 64 + lane) * 8];
            acc[ct] = __builtin_amdgcn_mfma_f32_16x16x32_bf16(Af, Bf, acc[ct], 0, 0, 0);
        }
    }
    int rbase = row0 + (lane >> 4) * 4;
    #pragma unroll
    for (int ct = 0; ct < 3; ++ct) {
        int col = ct * 16 + (lane & 15);
        if (col < NCLASS) {
            #pragma unroll
            for (int r = 0; r < 4; ++r) {
                int row = rbase + r;
                if (row < N_NODES)
                    hW2b[(size_t)row * NCLASS + col] = f2bf(acc[ct][r]);
            }
        }
    }
}

// ---------------- SPMM2 (bucketed) + bias + log-softmax -> out ----------------

__global__ __launch_bounds__(64) void k_spmm2b(const ushort* __restrict__ hW2b,
                                               const int* __restrict__ bstart,
                                               const int* __restrict__ bcur,
                                               const int2* __restrict__ binned,
                                               const float* __restrict__ b2,
                                               float* __restrict__ out) {
    __shared__ float acc[NPB * 64];          // 4 KB
    int lane = threadIdx.x;
    int b = blockIdx.x;
    int lf = lane < NCLASS ? lane : 0;
    #pragma unroll
    for (int n = 0; n < NPB; ++n) acc[n * 64 + lane] = 0.f;

    for (int s = 0; s < NSEG; ++s) {
        int j = bstart[s * NB + b], e = bcur[s * NB + b];
        for (; j + 8 <= e; j += 8) {
            int2 p[8];
            #pragma unroll
            for (int k = 0; k < 8; ++k) p[k] = binned[j + k];
            float g[8];
            #pragma unroll
            for (int k = 0; k < 8; ++k)
                g[k] = bf2f(hW2b[(p[k].x & 0xFFFF) * NCLASS + lf]);
            #pragma unroll
            for (int k = 0; k < 8; ++k)
                acc[(p[k].x >> 16) * 64 + lane] += __int_as_float(p[k].y) * g[k];
        }
        for (; j < e; ++j) {
            int2 p0 = binned[j];
            float g0 = bf2f(hW2b[(p0.x & 0xFFFF) * NCLASS + lf]);
            acc[(p0.x >> 16) * 64 + lane] += __int_as_float(p0.y) * g0;
        }
    }

    float bias = (lane < NCLASS) ? b2[lane] : 0.f;
    for (int n = 0; n < NPB; ++n) {
        float v = (lane < NCLASS) ? (acc[n * 64 + lane] + bias) : -INFINITY;
        float m = v;
        #pragma unroll
        for (int off = 32; off; off >>= 1) m = fmaxf(m, __shfl_xor(m, off));
        float ex = (lane < NCLASS) ? __expf(v - m) : 0.f;
        float ssum = ex;
        #pragma unroll
        for (int off = 32; off; off >>= 1) ssum += __shfl_xor(ssum, off);
        float ls = __logf(ssum);
        if (lane < NCLASS) {
            int node = b * NPB + n;
            out[(size_t)node * NCLASS + lane] = v;
            out[(size_t)N_NODES * NCLASS + (size_t)node * NCLASS + lane] = v - m - ls;
        }
    }
}

// ---------------- launch ----------------

extern "C" void kernel_launch(void* const* d_in, const int* in_sizes, int n_in,
                              void* d_out, int out_size, void* d_ws, size_t ws_size,
                              hipStream_t stream) {
    const float* x    = (const float*)d_in[0];
    const float* W1   = (const float*)d_in[1];
    const float* b1   = (const float*)d_in[2];
    const float* W2   = (const float*)d_in[3];
    const float* b2   = (const float*)d_in[4];
    const float* ewt  = (const float*)d_in[5];
    const int*   esrc = (const int*)d_in[6];
    const int*   edst = (const int*)d_in[7];
    float* out = (float*)d_out;

    // workspace layout (16B-aligned chunks)
    char* p = (char*)d_ws;
    ushort* xW1b = (ushort*)p;   p += (size_t)N_NODES * NHID * 2;      // 6.40 MB
    ushort* h_b  = (ushort*)p;   p += (size_t)NPAD_ROWS * NHID * 2;    // 6.41 MB
    ushort* hW2b = (ushort*)p;   p += (size_t)N_NODES * NCLASS * 2;    // 4.00 MB
    int2*   binned = (int2*)p;   p += (size_t)N_EDGES * 8;             // 6.40 MB
    ushort* W1f  = (ushort*)p;   p += 2048 * 8 * 2;                    // 32 KB
    ushort* W2f  = (ushort*)p;   p += 384 * 8 * 2;                     // 6 KB
    int* bcnt    = (int*)p;      p += NSEG * NB * 4;                   // 87.5 KB
    int* cursor  = (int*)p;      p += 4;
    int* bstart  = (int*)p;      p += NSEG * NB * 4;
    int* bcur    = (int*)p;      p += NSEG * NB * 4;

    hipMemsetAsync(bcnt, 0, (NSEG * NB + 1) * sizeof(int), stream);  // bcnt + cursor

    k_bhist<<<(N_EDGES + 255) / 256, 256, 0, stream>>>(edst, bcnt);
    k_bscan<<<(NSEG * NB + 255) / 256, 256, 0, stream>>>(bcnt, bstart, bcur, cursor);
    k_bin<<<(N_EDGES + 255) / 256, 256, 0, stream>>>(esrc, edst, ewt, bcur, binned);
    k_prep<<<10, 256, 0, stream>>>(W1, W2, W1f, W2f);

    k_gemm1<<<N_NODES / 16, 256, 0, stream>>>(x, W1f, xW1b);
    k_spmm1b<<<NB, 64, 0, stream>>>(xW1b, bstart, bcur, binned, b1, h_b);
    k_gemm2<<<NPAD_ROWS / 64, 256, 0, stream>>>(h_b, W2f, hW2b);
    k_spmm2b<<<NB, 64, 0, stream>>>(hW2b, bstart, bcur, binned, b2, out);
}